// Round 1
// 81.100 us; speedup vs baseline: 1.0695x; 1.0695x over previous
//
#include <hip/hip_runtime.h>
#include <hip/hip_bf16.h>
#include <stdint.h>

// Problem constants (fixed by the reference)
#define P 2048       // D_STATE
#define HN 64        // D_INPUT
#define L 16384      // kernel_size
#define BN 64        // l-columns per block (2 n-subtiles of 32)
#define KTW 16       // kt steps per wave (128 total / 8 waves)

typedef __bf16 bf16_t;
typedef bf16_t bf16x8 __attribute__((ext_vector_type(8)));
typedef float f32x16 __attribute__((ext_vector_type(16)));

__device__ __forceinline__ float2 cmul(float2 a, float2 b) {
    return make_float2(a.x * b.x - a.y * b.y, a.x * b.y + a.y * b.x);
}

__device__ __forceinline__ uint32_t packbf(float2 v) {
    union { __hip_bfloat162 v; uint32_t u; } cv;
    cv.v = __float22bfloat162_rn(make_float2(v.x, v.y));
    return cv.u;
}

// ---------------------------------------------------------------------------
// Prep: (a) W in bf16 32x32-MFMA A-fragment order: granule gid =
// ((kt*2+q)*2+mt)*64+lane holds A[m=mt*32+(lane&31)][k-run], p-run =
// kt*16 + q*8 + (lane>>5)*4, elements (W_re, -W_im) pairs (k=2p, 2p+1).
// (b) Tcol[p*32 + lc] = A_p^lc (float2), lc in [0,32) — block-invariant.
// (c) a32[p] = A_p^32 (for deriving the second base column in mv_main).
__global__ void mv_prep(const float* __restrict__ Win,
                        const float* __restrict__ Ain,
                        uint4* __restrict__ wexp,
                        float2* __restrict__ tcol,
                        float2* __restrict__ a32) {
    int gid = blockIdx.x * 256 + threadIdx.x;   // 32768
    {   // wexp
        int lane = gid & 63;
        int mt = (gid >> 6) & 1;
        int q = (gid >> 7) & 1;
        int kt = gid >> 8;
        int m = mt * 32 + (lane & 31);
        int p0 = kt * 16 + q * 8 + (lane >> 5) * 4;
        const float4* wp = (const float4*)(Win + (size_t)(m * P + p0) * 2);
        float4 f0 = wp[0], f1 = wp[1];
        float re[4] = {f0.x, f0.z, f1.x, f1.z};
        float im[4] = {f0.y, f0.w, f1.y, f1.w};
        uint32_t o[4];
#pragma unroll
        for (int j = 0; j < 4; ++j)
            o[j] = packbf(make_float2(re[j], -im[j]));
        wexp[gid] = make_uint4(o[0], o[1], o[2], o[3]);
    }
    {   // Tcol: thread handles p = gid>>4, lc = 2*(gid&15) and lc+1
        int p = gid >> 4;
        int e = gid & 15;                      // lc/2
        float2 a = *(const float2*)(Ain + 2 * p);
        float2 a2 = cmul(a, a);
        float2 r = make_float2(1.f, 0.f);
        float2 sq = a2;
#pragma unroll
        for (int b = 0; b < 4; ++b) {
            if ((e >> b) & 1) r = cmul(r, sq);
            sq = cmul(sq, sq);
        }
        float2 ro = cmul(r, a);
        tcol[(size_t)p * 32 + 2 * e] = r;       // A^(2e)
        tcol[(size_t)p * 32 + 2 * e + 1] = ro;  // A^(2e+1)
        if (e == 15) a32[p] = cmul(ro, a);      // A^32
    }
}

// ---------------------------------------------------------------------------
// Main: grid 256 x 512 thr (8 waves). Wave w: kt in [16w, 16w+16), both
// m-tiles AND both n-subtiles (nt). B-fragments generated in-register
// (Base_nt x Tcol); tv and wexp A-frags shared across nt. K-loop fully
// unrolled with ping-pong register sets (no rotation movs, no barriers).
// Final cross-wave reduction through LDS (reusing the Base buffer).
struct StepRegs {
    uint4 a[2][2];      // [mt][q] wexp A-fragments
    float2 tv[8];       // Tcol values [q*4+j]
};

__global__ void __launch_bounds__(512, 2) mv_main(
    const float* __restrict__ Ain,
    const uint4* __restrict__ wexp,
    const float2* __restrict__ Tcol,
    const float2* __restrict__ A32,
    float* __restrict__ out) {
    __shared__ __align__(16) float ldsp[8192];   // 32 KB: Base0|Base1, then Red

    const int t = threadIdx.x;
    const int bn = blockIdx.x;
    const int w = t >> 6;
    const int lw = t & 63;

    float2* Base0 = (float2*)ldsp;       // [P]  A_p^(64*bn)
    float2* Base1 = Base0 + P;           // [P]  A_p^(64*bn+32)

    {   // Base build (log-space, same numerics as reference); Base1 via A^32
        float e = (float)(BN * bn);
        const float2* Af2 = (const float2*)Ain;
#pragma unroll
        for (int j = 0; j < 4; ++j) {
            int p = t + 512 * j;
            float2 a = Af2[p];
            float logr = 0.5f * logf(a.x * a.x + a.y * a.y);
            float th = atan2f(a.y, a.x);
            float mag = expf(e * logr);
            float s, c;
            sincosf(e * th, &s, &c);
            float2 b0 = make_float2(mag * c, mag * s);
            Base0[p] = b0;
            Base1[p] = cmul(b0, A32[p]);
        }
    }
    __syncthreads();

    const int n = lw & 31;         // column within 32-wide tile
    const int kh = lw >> 5;        // k-half of the fragment
    const int kt0 = w * KTW;
    const float2* tc = Tcol + n;
    const float4* B0f4 = (const float4*)Base0;
    const float4* B1f4 = (const float4*)Base1;

    f32x16 acc[2][2];              // [mt][nt]
#pragma unroll
    for (int mt = 0; mt < 2; ++mt)
#pragma unroll
        for (int nt = 0; nt < 2; ++nt)
#pragma unroll
            for (int r = 0; r < 16; ++r) acc[mt][nt][r] = 0.f;

    StepRegs s0, s1;

    auto load_step = [&](int kt, StepRegs& s) {
#pragma unroll
        for (int q = 0; q < 2; ++q) {
#pragma unroll
            for (int mt = 0; mt < 2; ++mt)
                s.a[mt][q] = wexp[(size_t)(((kt * 2 + q) * 2 + mt) * 64 + lw)];
            int pb = kt * 16 + q * 8 + kh * 4;
#pragma unroll
            for (int j = 0; j < 4; ++j)
                s.tv[q * 4 + j] = tc[(size_t)(pb + j) * 32];
        }
    };

    auto compute_step = [&](int kt, const StepRegs& s) {
#pragma unroll
        for (int q = 0; q < 2; ++q) {
            int bi = kt * 8 + q * 4 + kh * 2;
            float4 c0 = B0f4[bi], c1 = B0f4[bi + 1];
            float4 d0 = B1f4[bi], d1 = B1f4[bi + 1];
            float2 bb[4] = {make_float2(c0.x, c0.y), make_float2(c0.z, c0.w),
                            make_float2(c1.x, c1.y), make_float2(c1.z, c1.w)};
            float2 dd[4] = {make_float2(d0.x, d0.y), make_float2(d0.z, d0.w),
                            make_float2(d1.x, d1.y), make_float2(d1.z, d1.w)};
            uint32_t f0[4], f1[4];
#pragma unroll
            for (int j = 0; j < 4; ++j) {
                float2 tvv = s.tv[q * 4 + j];
                f0[j] = packbf(cmul(bb[j], tvv));
                f1[j] = packbf(cmul(dd[j], tvv));
            }
            union { uint4 u; bf16x8 v; } F0, F1, A0, A1;
            F0.u = make_uint4(f0[0], f0[1], f0[2], f0[3]);
            F1.u = make_uint4(f1[0], f1[1], f1[2], f1[3]);
            A0.u = s.a[0][q];
            A1.u = s.a[1][q];
            acc[0][0] = __builtin_amdgcn_mfma_f32_32x32x16_bf16(A0.v, F0.v, acc[0][0], 0, 0, 0);
            acc[1][0] = __builtin_amdgcn_mfma_f32_32x32x16_bf16(A1.v, F0.v, acc[1][0], 0, 0, 0);
            acc[0][1] = __builtin_amdgcn_mfma_f32_32x32x16_bf16(A0.v, F1.v, acc[0][1], 0, 0, 0);
            acc[1][1] = __builtin_amdgcn_mfma_f32_32x32x16_bf16(A1.v, F1.v, acc[1][1], 0, 0, 0);
        }
    };

    load_step(kt0, s0);
#pragma unroll
    for (int i = 0; i < KTW; i += 2) {
        if (i + 1 < KTW) load_step(kt0 + i + 1, s1);
        compute_step(kt0 + i, s0);
        if (i + 2 < KTW) load_step(kt0 + i + 2, s0);
        if (i + 1 < KTW) compute_step(kt0 + i + 1, s1);
    }

    // ---- cross-wave reduction (LDS reused: Base is dead) ----
    __syncthreads();
    float* Red = ldsp;                 // 8 waves x 1024 floats
    // C/D layout (m74): col = lane&31, row = (r&3) + 8*(r>>2) + 4*(lane>>5)
    const int row = t >> 4;            // 0..31
    const int colb = (t & 15) * 2;     // even column
    const int rr = (row & 3) | ((row >> 3) << 2);
    const int lane0 = colb + ((row >> 2) & 1) * 32;

#pragma unroll
    for (int mt = 0; mt < 2; ++mt)
#pragma unroll
        for (int nt = 0; nt < 2; ++nt) {
#pragma unroll
            for (int r = 0; r < 16; ++r)
                Red[w * 1024 + r * 64 + lw] = acc[mt][nt][r];
            __syncthreads();
            float sx = 0.f, sy = 0.f;
#pragma unroll
            for (int ww = 0; ww < 8; ++ww) {
                sx += Red[ww * 1024 + rr * 64 + lane0];
                sy += Red[ww * 1024 + rr * 64 + lane0 + 1];
            }
            float2 o2 = make_float2(sx, sy);
            *(float2*)(out + (size_t)(mt * 32 + row) * L + (size_t)bn * BN + nt * 32 + colb) = o2;
            __syncthreads();
        }
}

// ---------------------------------------------------------------------------
extern "C" void kernel_launch(void* const* d_in, const int* in_sizes, int n_in,
                              void* d_out, int out_size, void* d_ws, size_t ws_size,
                              hipStream_t stream) {
    const float* Ain = nullptr;
    const float* Win = nullptr;
    for (int i = 0; i < n_in; ++i) {
        if (in_sizes[i] == 2 * P) Ain = (const float*)d_in[i];
        else if (in_sizes[i] == 2 * HN * P) Win = (const float*)d_in[i];
    }
    if (!Ain) Ain = (const float*)d_in[0];
    if (!Win) Win = (const float*)d_in[1];
    (void)out_size; (void)ws_size;
    uint4* wexp = (uint4*)d_ws;                                  // 512 KB
    float2* tcol = (float2*)((char*)d_ws + 512 * 1024);          // +512 KB
    float2* a32 = (float2*)((char*)d_ws + 1024 * 1024);          // +16 KB
    mv_prep<<<128, 256, 0, stream>>>(Win, Ain, wexp, tcol, a32);
    mv_main<<<L / BN, 512, 0, stream>>>(Ain, wexp, tcol, a32, (float*)d_out);
}